// Round 1
// baseline (1292.578 us; speedup 1.0000x reference)
//
#include <hip/hip_runtime.h>
#include <hip/hip_bf16.h>

#define BATCH 64
#define SEQT  2048
#define FEAT  64
#define HID   128
#define G4    512              // 4*HID
#define CHUNK 16
#define NCHUNK (SEQT / CHUNK)  // 128
#define XSP  68                // xs row stride (floats), padded vs 64
#define H1P  136               // h1c row stride (shorts), padded vs 128
#define XZP  516               // xzbuf row stride (floats), padded vs 512

using short8  = __attribute__((ext_vector_type(8))) short;   // 8 x bf16 (4 VGPRs)
using floatx4 = __attribute__((ext_vector_type(4))) float;   // MFMA C/D

// ---------- math helpers ----------
__device__ __forceinline__ float sigmoidf_(float x) {
    return __builtin_amdgcn_rcpf(1.0f + __expf(-x));
}
__device__ __forceinline__ float seluf_(float x) {
    const float a = 1.6732632423543772f;
    const float s = 1.0507009873554805f;
    return x > 0.0f ? s * x : s * a * (__expf(x) - 1.0f);
}
// fp32 -> bf16 bits, round-to-nearest-even
__device__ __forceinline__ unsigned short f2bf_(float f) {
    unsigned u = __float_as_uint(f);
    u += 0x7FFFu + ((u >> 16) & 1u);
    return (unsigned short)(u >> 16);
}

// ---------- fused two-layer LSTM, wavefront-pipelined ----------
// 128 blocks x 512 threads, all co-resident (<= 256 CUs -> no deadlock).
// Blocks [0,64):   layer 1, row b. Per chunk: builds xz1 = x@W1+b1 in LDS via
//                  MFMA (input projection folded in -- no separate GEMM pass),
//                  runs 16 recurrent steps, publishes bf16 h1 chunk via
//                  WRITE-THROUGH relaxed agent atomics (sc-bits -> coherent at
//                  the memory-side Infinity Cache; no wbl2), then a relaxed
//                  flag store.  Ordering: __syncthreads drains vmcnt(0) per
//                  wave, so all data stores reached the coherence point
//                  before the flag store issues.
// Blocks [64,128): layer 2, row b. Polls flag (relaxed agent load), stages h1
//                  chunk via relaxed agent atomic loads (cache-bypassing ->
//                  no stale L1/L2, no invalidates), builds xz2 = h1c@W2+b2
//                  via MFMA, runs 16 rec steps, writes fp32 h2 to out.
__global__ __launch_bounds__(512)
__attribute__((amdgpu_waves_per_eu(2, 2)))
void fused_lstm(const float* __restrict__ x,                 // [B][T][64] fp32
                const float* __restrict__ W1,                // [64][512] fp32
                const float* __restrict__ U1,                // [128][512] fp32
                const float* __restrict__ b1,                // [512]
                const float* __restrict__ W2,                // [128][512] fp32
                const float* __restrict__ U2,
                const float* __restrict__ b2,
                unsigned long long* __restrict__ h1g,        // [B][T][128] bf16 (ws), u64 view
                unsigned* __restrict__ flags,                // [B] (zeroed by memset)
                float* __restrict__ out) {                   // [B][T][128] fp32
    const bool l2  = blockIdx.x >= BATCH;
    const int  b   = l2 ? ((int)blockIdx.x - BATCH) : (int)blockIdx.x;
    const int tid  = threadIdx.x;
    const int w    = tid >> 6;
    const int lane = tid & 63;
    const int c16  = lane & 15;
    const int quad = lane >> 4;
    const int j    = w * 16 + c16;            // output column this thread owns

    __shared__ __align__(16) short hA[2][HID];           // bf16 h ping-pong
    __shared__ __align__(16) float xzbuf[CHUNK * XZP];   // fp32 z-pre, gate-interleaved, padded
    __shared__ __align__(16) float xs[CHUNK * XSP];      // l1: x chunk staged (padded)
    __shared__ __align__(16) short h1c[CHUNK * H1P];     // l2: h1 chunk staged (padded)
    __shared__ __align__(16) short h1buf[CHUNK * HID];   // l1: h chunk bf16 (flush buffer)
    __shared__ __align__(16) float hbuf[CHUNK * HID];    // l2: h chunk fp32 (out buffer)

    // ---- stage recurrent-weight fragments U (l1->U1, l2->U2), K=128 ----
    const float* U = l2 ? U2 : U1;
    short8 bfrag[4][4];
#pragma unroll
    for (int g = 0; g < 4; ++g) {
        const float* Ucol = U + (size_t)(g * 128 + j);
#pragma unroll
        for (int kc = 0; kc < 4; ++kc) {
            short8 v;
#pragma unroll
            for (int jj = 0; jj < 8; ++jj) {
                int k = kc * 32 + quad * 8 + jj;
                v[jj] = (short)f2bf_(Ucol[(size_t)k * G4]);
            }
            bfrag[g][kc] = v;
        }
    }

    // ---- stage input-projection fragments: l1 -> W1 (K=64, kc<2), l2 -> W2 (K=128) ----
    const float* Wp = l2 ? W2 : W1;
    short8 wfrag[4][4];
#pragma unroll
    for (int g = 0; g < 4; ++g) {
        const float* Wcol = Wp + (size_t)(g * 128 + j);
#pragma unroll
        for (int kc = 0; kc < 4; ++kc) {
            short8 v;
            if (l2 || kc < 2) {
#pragma unroll
                for (int jj = 0; jj < 8; ++jj) {
                    int k = kc * 32 + quad * 8 + jj;
                    v[jj] = (short)f2bf_(Wcol[(size_t)k * G4]);
                }
            } else {
#pragma unroll
                for (int jj = 0; jj < 8; ++jj) v[jj] = 0;
            }
            wfrag[g][kc] = v;
        }
    }
    const float* bb = l2 ? b2 : b1;
    const float4 bias4 = make_float4(bb[j], bb[128 + j], bb[256 + j], bb[384 + j]);

    const float* xb = x + (size_t)b * SEQT * FEAT;
    if (!l2) {   // prologue: stage x chunk 0 into padded LDS
        if (tid < 256) {
            float4 v = ((const float4*)xb)[tid];
            int t = tid >> 4, k4 = (tid & 15) << 2;
            *(float4*)&xs[t * XSP + k4] = v;
        }
    }
    if (tid < HID) hA[0][tid] = 0;            // h(-1) = 0
    float cst = 0.0f;                          // cell state (replicated x4 quads)
    floatx4 zero4 = {0.f, 0.f, 0.f, 0.f};
    __syncthreads();

    float*              out_b  = out + (size_t)b * SEQT * HID;
    unsigned long long* h1g_b  = h1g + (size_t)b * (SEQT * HID / 4);  // 65536 u64 per row

    for (int c = 0; c < NCHUNK; ++c) {
        float4 pf;
        if (!l2) {
            // prefetch next x chunk (4 KB, contiguous)
            if (c + 1 < NCHUNK && tid < 256)
                pf = ((const float4*)(xb + (size_t)(c + 1) * CHUNK * FEAT))[tid];
            // ---- build xz1 chunk: [16 timesteps] x [512] = x_s @ W1 + b1, K=64 ----
            short8 axf[2];
#pragma unroll
            for (int kc = 0; kc < 2; ++kc) {
                const float* p = &xs[c16 * XSP + kc * 32 + quad * 8];
                float4 f0 = *(const float4*)p;
                float4 f1 = *(const float4*)(p + 4);
                short8 v;
                v[0] = (short)f2bf_(f0.x); v[1] = (short)f2bf_(f0.y);
                v[2] = (short)f2bf_(f0.z); v[3] = (short)f2bf_(f0.w);
                v[4] = (short)f2bf_(f1.x); v[5] = (short)f2bf_(f1.y);
                v[6] = (short)f2bf_(f1.z); v[7] = (short)f2bf_(f1.w);
                axf[kc] = v;
            }
            floatx4 acc1[4];
#pragma unroll
            for (int g = 0; g < 4; ++g)
                acc1[g] = __builtin_amdgcn_mfma_f32_16x16x32_bf16(axf[0], wfrag[g][0], zero4, 0, 0, 0);
#pragma unroll
            for (int g = 0; g < 4; ++g)
                acc1[g] = __builtin_amdgcn_mfma_f32_16x16x32_bf16(axf[1], wfrag[g][1], acc1[g], 0, 0, 0);
            // D mapping: col=lane&15 (our j), row=quad*4+reg (timestep)
#pragma unroll
            for (int r = 0; r < 4; ++r) {
                int s = quad * 4 + r;
                *(float4*)&xzbuf[s * XZP + j * 4] =
                    make_float4(acc1[0][r] + bias4.x, acc1[1][r] + bias4.y,
                                acc1[2][r] + bias4.z, acc1[3][r] + bias4.w);
            }
            __syncthreads();
        } else {
            // ---- wait for layer-1 chunk c, then stage + build xz2 chunk ----
            if (tid == 0) {
                while (__hip_atomic_load(&flags[b], __ATOMIC_RELAXED,
                                         __HIP_MEMORY_SCOPE_AGENT) < (unsigned)(c + 1))
                    __builtin_amdgcn_s_sleep(8);
            }
            __syncthreads();
            // stage h1 chunk: 512 x 8B cache-bypassing loads (coherent at IC)
            {
                unsigned long long hv = __hip_atomic_load(
                    h1g_b + (size_t)c * 512 + tid, __ATOMIC_RELAXED, __HIP_MEMORY_SCOPE_AGENT);
                int t = tid >> 5, kg = tid & 31;
                *(unsigned long long*)&h1c[t * H1P + kg * 4] = hv;
            }
            __syncthreads();

            // xz2[t][n] = sum_k h1c[t][k] * W2[k][n] + b2  (M=16 timesteps, K=128)
            short8 af2[4];
#pragma unroll
            for (int kc = 0; kc < 4; ++kc)
                af2[kc] = *(const short8*)&h1c[c16 * H1P + kc * 32 + quad * 8];
            floatx4 acc2[4];
#pragma unroll
            for (int g = 0; g < 4; ++g)
                acc2[g] = __builtin_amdgcn_mfma_f32_16x16x32_bf16(af2[0], wfrag[g][0], zero4, 0, 0, 0);
#pragma unroll
            for (int kc = 1; kc < 4; ++kc)
#pragma unroll
                for (int g = 0; g < 4; ++g)
                    acc2[g] = __builtin_amdgcn_mfma_f32_16x16x32_bf16(af2[kc], wfrag[g][kc], acc2[g], 0, 0, 0);
#pragma unroll
            for (int r = 0; r < 4; ++r) {
                int s = quad * 4 + r;
                *(float4*)&xzbuf[s * XZP + j * 4] =
                    make_float4(acc2[0][r] + bias4.x, acc2[1][r] + bias4.y,
                                acc2[2][r] + bias4.z, acc2[3][r] + bias4.w);
            }
            __syncthreads();
        }

        // ---- 16 recurrent steps ----
#pragma unroll 2
        for (int s = 0; s < CHUNK; ++s) {
            const short* hb = &hA[s & 1][0];
            short8 af[4];
#pragma unroll
            for (int kc = 0; kc < 4; ++kc)
                af[kc] = *(const short8*)&hb[kc * 32 + quad * 8];

            float4 xq = *(const float4*)&xzbuf[s * XZP + j * 4];

            floatx4 acc[4];
#pragma unroll
            for (int g = 0; g < 4; ++g)
                acc[g] = __builtin_amdgcn_mfma_f32_16x16x32_bf16(af[0], bfrag[g][0], zero4, 0, 0, 0);
#pragma unroll
            for (int kc = 1; kc < 4; ++kc)
#pragma unroll
                for (int g = 0; g < 4; ++g)
                    acc[g] = __builtin_amdgcn_mfma_f32_16x16x32_bf16(af[kc], bfrag[g][kc], acc[g], 0, 0, 0);

            float zi = acc[0][0] + xq.x;
            float zf = acc[1][0] + xq.y;
            float zg = acc[2][0] + xq.z;
            float zo = acc[3][0] + xq.w;
            float ig = sigmoidf_(zi);
            float fg = sigmoidf_(zf);
            float gg = seluf_(zg);
            float og = sigmoidf_(zo);
            cst = fg * cst + ig * gg;
            float h = og * seluf_(cst);

            if (lane < 16) {                   // quad 0 publishes (all quads identical)
                unsigned short hb16 = f2bf_(h);
                hA[(s + 1) & 1][j] = (short)hb16;
                if (l2) hbuf[s * HID + j] = h;
                else    h1buf[s * HID + j] = (short)hb16;
            }
            __syncthreads();
        }

        // ---- chunk boundary ----
        if (!l2) {
            // flush h1 chunk: 512 x 8B write-through stores (coherent at IC, no wbl2)
            unsigned long long hv = *(const unsigned long long*)&h1buf[tid * 4];
            __hip_atomic_store(h1g_b + (size_t)c * 512 + tid, hv,
                               __ATOMIC_RELAXED, __HIP_MEMORY_SCOPE_AGENT);
            // install prefetched x chunk
            if (c + 1 < NCHUNK && tid < 256) {
                int t = tid >> 4, k4 = (tid & 15) << 2;
                *(float4*)&xs[t * XSP + k4] = pf;
            }
            __syncthreads();   // per-wave vmcnt(0) drain: h1 stores reached IC
            if (tid == 0)
                __hip_atomic_store(&flags[b], (unsigned)(c + 1),
                                   __ATOMIC_RELAXED, __HIP_MEMORY_SCOPE_AGENT);
        } else {
            float4 hv = *(const float4*)&hbuf[tid * 4];
            *(float4*)&out_b[(size_t)c * CHUNK * HID + tid * 4] = hv;
            // next chunk's spin+syncthreads protects hbuf reuse
        }
    }
}

// ---------- host launch ----------
// ws layout:
//   [0, 32 MB)        h1 bf16  (layer-1 -> layer-2 pipe, IC-coherent atomics)
//   [32 MB, +256 B)   per-row chunk flags (zeroed via memsetAsync each call)
extern "C" void kernel_launch(void* const* d_in, const int* in_sizes, int n_in,
                              void* d_out, int out_size, void* d_ws, size_t ws_size,
                              hipStream_t stream) {
    const float* x  = (const float*)d_in[0];
    const float* W1 = (const float*)d_in[1];
    const float* U1 = (const float*)d_in[2];
    const float* b1 = (const float*)d_in[3];
    const float* W2 = (const float*)d_in[4];
    const float* U2 = (const float*)d_in[5];
    const float* b2 = (const float*)d_in[6];
    float* out = (float*)d_out;

    const size_t BT       = (size_t)BATCH * SEQT;
    const size_t H1_BYTES = BT * HID * 2;    // 32 MB

    unsigned long long* h1g   = (unsigned long long*)d_ws;
    unsigned*           flags = (unsigned*)((char*)d_ws + H1_BYTES);

    hipMemsetAsync(flags, 0, BATCH * sizeof(unsigned), stream);

    fused_lstm<<<dim3(2 * BATCH), dim3(512), 0, stream>>>(
        x, W1, U1, b1, W2, U2, b2, h1g, flags, out);
}